// Round 1
// baseline (1177.914 us; speedup 1.0000x reference)
//
#include <hip/hip_runtime.h>
#include <math.h>

#define N_NODES 50000
#define N_EDGES 400000
#define CHUNK   100
#define NCH     2
#define OUTC    96
#define HID     192      // NCH*OUTC
#define HID2    384      // 2*HID
#define EPS     1e-5f

// ---------------- projection: Linear(100->96) x2 chunks + LN(96) + LeakyReLU ----------------
// block = 128 threads (2 waves), wave c handles chunk c; 8 nodes per block.
__global__ __launch_bounds__(128) void proj_kernel(
    const float* __restrict__ h, const float* __restrict__ W,
    const float* __restrict__ b, const float* __restrict__ g,
    const float* __restrict__ beta, float* __restrict__ hh)
{
    __shared__ float xs[8][NCH * CHUNK];
    const int tid  = threadIdx.x;
    const int nbase = blockIdx.x * 8;
    for (int i = tid; i < 8 * NCH * CHUNK; i += 128) {
        int ni = i / (NCH * CHUNK), f = i % (NCH * CHUNK);
        int n = nbase + ni;
        xs[ni][f] = (n < N_NODES) ? h[(size_t)n * (NCH * CHUNK) + f] : 0.f;
    }
    __syncthreads();
    const int c    = tid >> 6;     // wave index = chunk
    const int lane = tid & 63;
    const float* wc = &W[c * CHUNK * OUTC];

    for (int ni = 0; ni < 8; ++ni) {
        int n = nbase + ni;
        if (n >= N_NODES) break;
        const float* xc = &xs[ni][c * CHUNK];
        float acc0 = b[c * OUTC + lane];
        float acc1 = (lane < 32) ? b[c * OUTC + 64 + lane] : 0.f;
        for (int d = 0; d < CHUNK; ++d) {
            float xv = xc[d];
            acc0 += xv * wc[d * OUTC + lane];
            float w1 = (lane < 32) ? wc[d * OUTC + 64 + lane] : 0.f;
            acc1 += xv * w1;
        }
        // LN over 96 values held as acc0 (all lanes) + acc1 (lanes<32)
        float v1 = (lane < 32) ? acc1 : 0.f;
        float s  = acc0 + v1;
        float s2 = acc0 * acc0 + v1 * v1;
        for (int off = 32; off > 0; off >>= 1) {
            s  += __shfl_xor(s,  off, 64);
            s2 += __shfl_xor(s2, off, 64);
        }
        float mean = s * (1.f / 96.f);
        float var  = s2 * (1.f / 96.f) - mean * mean;
        float rstd = rsqrtf(var + EPS);

        float y0 = (acc0 - mean) * rstd * g[c * OUTC + lane] + beta[c * OUTC + lane];
        y0 = (y0 < 0.f) ? 0.01f * y0 : y0;
        hh[(size_t)n * HID + c * OUTC + lane] = y0;
        if (lane < 32) {
            float y1 = (acc1 - mean) * rstd * g[c * OUTC + 64 + lane] + beta[c * OUTC + 64 + lane];
            y1 = (y1 < 0.f) ? 0.01f * y1 : y1;
            hh[(size_t)n * HID + c * OUTC + 64 + lane] = y1;
        }
    }
}

// ---------------- CSR build ----------------
__global__ void zero_deg_kernel(int* __restrict__ deg)
{
    int i = blockIdx.x * blockDim.x + threadIdx.x;
    if (i < N_NODES) deg[i] = 0;
}

__global__ void count_kernel(const int* __restrict__ dst, int* __restrict__ deg)
{
    int e = blockIdx.x * blockDim.x + threadIdx.x;
    if (e < N_EDGES) atomicAdd(&deg[dst[e]], 1);
}

__global__ __launch_bounds__(1024) void scan_kernel(
    const int* __restrict__ deg, int* __restrict__ rowstart,
    int* __restrict__ cursor, float* __restrict__ norm)
{
    __shared__ int sums[1024];
    const int t = threadIdx.x;
    const int L = (N_NODES + 1023) / 1024;   // 49
    int lo = t * L, hi = min(lo + L, N_NODES);
    int s = 0;
    for (int i = lo; i < hi; ++i) s += deg[i];
    sums[t] = s;
    __syncthreads();
    if (t == 0) {
        int run = 0;
        for (int i = 0; i < 1024; ++i) { int v = sums[i]; sums[i] = run; run += v; }
        rowstart[N_NODES] = run;
    }
    __syncthreads();
    int off = sums[t];
    for (int i = lo; i < hi; ++i) {
        int d = deg[i];
        rowstart[i] = off;
        cursor[i]   = off;
        norm[i]     = (d > 0) ? 1.f / (float)d : 0.f;
        off += d;
    }
}

__global__ void fill_kernel(const int* __restrict__ dst, int* __restrict__ cursor,
                            int* __restrict__ eidx)
{
    int e = blockIdx.x * blockDim.x + threadIdx.x;
    if (e < N_EDGES) {
        int pos = atomicAdd(&cursor[dst[e]], 1);
        eidx[pos] = e;
    }
}

// ---------------- aggregation (gather form): ahn[v] = norm[v] * sum_{e: dst=v} hh[src[e]] * dist[e]
// block = 256 (4 waves), one node per wave; lane holds features lane, lane+64, lane+128.
__global__ __launch_bounds__(256) void aggregate_kernel(
    const float* __restrict__ hh, const float* __restrict__ dist,
    const int* __restrict__ src, const int* __restrict__ eidx,
    const int* __restrict__ rowstart, const float* __restrict__ norm,
    float* __restrict__ ahn)
{
    const int wave = threadIdx.x >> 6;
    const int lane = threadIdx.x & 63;
    const int v = blockIdx.x * 4 + wave;
    if (v >= N_NODES) return;
    const int r0 = rowstart[v], r1 = rowstart[v + 1];
    float a0 = 0.f, a1 = 0.f, a2 = 0.f;
    for (int k = r0; k < r1; ++k) {
        int e = eidx[k];
        int sn = src[e];
        float dv = dist[e];
        const float* hs = &hh[(size_t)sn * HID];
        a0 += hs[lane]       * dv;
        a1 += hs[lane + 64]  * dv;
        a2 += hs[lane + 128] * dv;
    }
    float nm = norm[v];
    ahn[(size_t)v * HID + lane]       = a0 * nm;
    ahn[(size_t)v * HID + lane + 64]  = a1 * nm;
    ahn[(size_t)v * HID + lane + 128] = a2 * nm;
}

// ---------------- GcnSAGE update: hh[n] = relu(LN(concat(hh[n], ahn[n]) @ W + b))
// block = 192 threads (thread = output column), 16 nodes per block, W streamed from L2.
__global__ __launch_bounds__(192) void update_kernel(
    float* __restrict__ hh, const float* __restrict__ ahn,
    const float* __restrict__ W, const float* __restrict__ b,
    const float* __restrict__ g, const float* __restrict__ beta)
{
    __shared__ float hcs[16][HID2];      // 24.6 KB
    __shared__ float red[2][16][12];
    __shared__ float mv[2][16];
    const int tid = threadIdx.x;
    const int nbase = blockIdx.x * 16;

    for (int i = 0; i < 16; ++i) {
        int n = nbase + i;
        hcs[i][tid]       = hh[(size_t)n * HID + tid];
        hcs[i][HID + tid] = ahn[(size_t)n * HID + tid];
    }
    __syncthreads();

    float acc[16];
    float bb0 = b[tid];
    #pragma unroll
    for (int i = 0; i < 16; ++i) acc[i] = bb0;

    for (int d = 0; d < HID2; d += 4) {
        float w0 = W[(d + 0) * HID + tid];
        float w1 = W[(d + 1) * HID + tid];
        float w2 = W[(d + 2) * HID + tid];
        float w3 = W[(d + 3) * HID + tid];
        #pragma unroll
        for (int i = 0; i < 16; ++i) {
            float4 hv = *(const float4*)&hcs[i][d];
            acc[i] += hv.x * w0 + hv.y * w1 + hv.z * w2 + hv.w * w3;
        }
    }
    __syncthreads();
    // LN reduction: reuse hcs as ys[16][192]
    float* ys = &hcs[0][0];
    #pragma unroll
    for (int i = 0; i < 16; ++i) ys[i * HID + tid] = acc[i];
    __syncthreads();
    {
        int i = tid / 12, j = tid % 12;
        float s = 0.f, s2 = 0.f;
        for (int k = j; k < HID; k += 12) { float v = ys[i * HID + k]; s += v; s2 += v * v; }
        red[0][i][j] = s; red[1][i][j] = s2;
    }
    __syncthreads();
    if (tid < 16) {
        float s = 0.f, s2 = 0.f;
        for (int j = 0; j < 12; ++j) { s += red[0][tid][j]; s2 += red[1][tid][j]; }
        float mean = s * (1.f / HID);
        float var  = s2 * (1.f / HID) - mean * mean;
        mv[0][tid] = mean;
        mv[1][tid] = rsqrtf(var + EPS);
    }
    __syncthreads();
    float gg = g[tid], be = beta[tid];
    #pragma unroll
    for (int i = 0; i < 16; ++i) {
        float y = (acc[i] - mv[0][i]) * mv[1][i] * gg + be;
        hh[(size_t)(nbase + i) * HID + tid] = (y > 0.f) ? y : 0.f;
    }
}

// ---------------- edge MLP: score = relu((h_src*h_dst) @ W1 + b1) @ W2 + b2
// block = 192 threads, 32 edges per block; threads split into 2 groups of 96 columns x 16 edges.
__global__ __launch_bounds__(192) void edge_kernel(
    const float* __restrict__ hh, const int* __restrict__ src, const int* __restrict__ dst,
    const float* __restrict__ W1, const float* __restrict__ b1,
    const float* __restrict__ W2, const float* __restrict__ b2,
    float* __restrict__ out)
{
    __shared__ float hes[32][HID];        // 24.6 KB
    __shared__ float hids[32][OUTC + 1];  // padded: kills 32-way bank conflict in reduce
    __shared__ int   sidx[32], didx[32];
    const int tid = threadIdx.x;
    const int ebase = blockIdx.x * 32;

    if (tid < 32) { sidx[tid] = src[ebase + tid]; didx[tid] = dst[ebase + tid]; }
    __syncthreads();
    for (int i = 0; i < 32; ++i) {
        hes[i][tid] = hh[(size_t)sidx[i] * HID + tid] * hh[(size_t)didx[i] * HID + tid];
    }
    __syncthreads();

    const int j    = tid % OUTC;         // hidden column
    const int eoff = (tid / OUTC) * 16;  // which 16-edge group
    float acc[16];
    float bj = b1[j];
    #pragma unroll
    for (int i = 0; i < 16; ++i) acc[i] = bj;

    for (int d = 0; d < HID; d += 4) {
        float w0 = W1[(d + 0) * OUTC + j];
        float w1 = W1[(d + 1) * OUTC + j];
        float w2 = W1[(d + 2) * OUTC + j];
        float w3 = W1[(d + 3) * OUTC + j];
        #pragma unroll
        for (int i = 0; i < 16; ++i) {
            float4 hv = *(const float4*)&hes[eoff + i][d];
            acc[i] += hv.x * w0 + hv.y * w1 + hv.z * w2 + hv.w * w3;
        }
    }
    #pragma unroll
    for (int i = 0; i < 16; ++i) hids[eoff + i][j] = fmaxf(acc[i], 0.f);
    __syncthreads();

    if (tid < 64) {
        int i = tid >> 1, c = tid & 1;
        float sc = b2[c];
        for (int k = 0; k < OUTC; ++k) sc += hids[i][k] * W2[k * 2 + c];
        out[(size_t)(ebase + i) * 2 + c] = sc;
    }
}

// ---------------- launch ----------------
extern "C" void kernel_launch(void* const* d_in, const int* in_sizes, int n_in,
                              void* d_out, int out_size, void* d_ws, size_t ws_size,
                              hipStream_t stream)
{
    const float* h         = (const float*)d_in[0];
    const float* dist      = (const float*)d_in[1];
    const int*   src       = (const int*)  d_in[2];
    const int*   dst       = (const int*)  d_in[3];
    const float* proj_W    = (const float*)d_in[4];
    const float* proj_b    = (const float*)d_in[5];
    const float* proj_g    = (const float*)d_in[6];
    const float* proj_beta = (const float*)d_in[7];
    const float* gcn_W     = (const float*)d_in[8];
    const float* gcn_b     = (const float*)d_in[9];
    const float* gcn_g     = (const float*)d_in[10];
    const float* gcn_beta  = (const float*)d_in[11];
    const float* ep_W1     = (const float*)d_in[12];
    const float* ep_b1     = (const float*)d_in[13];
    const float* ep_W2     = (const float*)d_in[14];
    const float* ep_b2     = (const float*)d_in[15];
    float* out = (float*)d_out;

    char* p = (char*)d_ws;
    float* hh  = (float*)p;  p += (size_t)N_NODES * HID * sizeof(float);
    float* ahn = (float*)p;  p += (size_t)N_NODES * HID * sizeof(float);
    float* nrm = (float*)p;  p += (size_t)N_NODES * sizeof(float);
    int* deg      = (int*)p; p += (size_t)N_NODES * sizeof(int);
    int* rowstart = (int*)p; p += (size_t)(N_NODES + 1) * sizeof(int);
    int* cursor   = (int*)p; p += (size_t)N_NODES * sizeof(int);
    int* eidx     = (int*)p; p += (size_t)N_EDGES * sizeof(int);

    // projection
    proj_kernel<<<(N_NODES + 7) / 8, 128, 0, stream>>>(h, proj_W, proj_b, proj_g, proj_beta, hh);
    // CSR build
    zero_deg_kernel<<<(N_NODES + 255) / 256, 256, 0, stream>>>(deg);
    count_kernel<<<(N_EDGES + 255) / 256, 256, 0, stream>>>(dst, deg);
    scan_kernel<<<1, 1024, 0, stream>>>(deg, rowstart, cursor, nrm);
    fill_kernel<<<(N_EDGES + 255) / 256, 256, 0, stream>>>(dst, cursor, eidx);
    // 2 GcnSAGE layers
    for (int l = 0; l < 2; ++l) {
        aggregate_kernel<<<(N_NODES + 3) / 4, 256, 0, stream>>>(hh, dist, src, eidx, rowstart, nrm, ahn);
        update_kernel<<<N_NODES / 16, 192, 0, stream>>>(
            hh, ahn, gcn_W + (size_t)l * HID2 * HID, gcn_b + l * HID,
            gcn_g + l * HID, gcn_beta + l * HID);
    }
    // edge MLP
    edge_kernel<<<N_EDGES / 32, 192, 0, stream>>>(hh, src, dst, ep_W1, ep_b1, ep_W2, ep_b2, out);
}

// Round 2
// 985.315 us; speedup vs baseline: 1.1955x; 1.1955x over previous
//
#include <hip/hip_runtime.h>
#include <math.h>

#define N_NODES 50000
#define N_EDGES 400000
#define CHUNK   100
#define NCH     2
#define OUTC    96
#define HID     192      // NCH*OUTC
#define HID2    384      // 2*HID
#define EPS     1e-5f

typedef __bf16 bf16x8 __attribute__((ext_vector_type(8)));
typedef float  f32x4  __attribute__((ext_vector_type(4)));

__device__ inline unsigned short f2bf(float f) {
    unsigned int u = __float_as_uint(f);
    unsigned int r = (u + 0x7FFFu + ((u >> 16) & 1u)) >> 16;   // RNE
    return (unsigned short)r;
}

// ---------------- projection: Linear(100->96) x2 chunks + LN(96) + LeakyReLU ----------------
__global__ __launch_bounds__(128) void proj_kernel(
    const float* __restrict__ h, const float* __restrict__ W,
    const float* __restrict__ b, const float* __restrict__ g,
    const float* __restrict__ beta, float* __restrict__ hh)
{
    __shared__ float xs[8][NCH * CHUNK];
    const int tid  = threadIdx.x;
    const int nbase = blockIdx.x * 8;
    for (int i = tid; i < 8 * NCH * CHUNK; i += 128) {
        int ni = i / (NCH * CHUNK), f = i % (NCH * CHUNK);
        int n = nbase + ni;
        xs[ni][f] = (n < N_NODES) ? h[(size_t)n * (NCH * CHUNK) + f] : 0.f;
    }
    __syncthreads();
    const int c    = tid >> 6;     // wave index = chunk
    const int lane = tid & 63;
    const float* wc = &W[c * CHUNK * OUTC];

    for (int ni = 0; ni < 8; ++ni) {
        int n = nbase + ni;
        if (n >= N_NODES) break;
        const float* xc = &xs[ni][c * CHUNK];
        float acc0 = b[c * OUTC + lane];
        float acc1 = (lane < 32) ? b[c * OUTC + 64 + lane] : 0.f;
        for (int d = 0; d < CHUNK; ++d) {
            float xv = xc[d];
            acc0 += xv * wc[d * OUTC + lane];
            float w1 = (lane < 32) ? wc[d * OUTC + 64 + lane] : 0.f;
            acc1 += xv * w1;
        }
        float v1 = (lane < 32) ? acc1 : 0.f;
        float s  = acc0 + v1;
        float s2 = acc0 * acc0 + v1 * v1;
        for (int off = 32; off > 0; off >>= 1) {
            s  += __shfl_xor(s,  off, 64);
            s2 += __shfl_xor(s2, off, 64);
        }
        float mean = s * (1.f / 96.f);
        float var  = s2 * (1.f / 96.f) - mean * mean;
        float rstd = rsqrtf(var + EPS);

        float y0 = (acc0 - mean) * rstd * g[c * OUTC + lane] + beta[c * OUTC + lane];
        y0 = (y0 < 0.f) ? 0.01f * y0 : y0;
        hh[(size_t)n * HID + c * OUTC + lane] = y0;
        if (lane < 32) {
            float y1 = (acc1 - mean) * rstd * g[c * OUTC + 64 + lane] + beta[c * OUTC + 64 + lane];
            y1 = (y1 < 0.f) ? 0.01f * y1 : y1;
            hh[(size_t)n * HID + c * OUTC + 64 + lane] = y1;
        }
    }
}

// ---------------- CSR build ----------------
__global__ void zero_deg_kernel(int* __restrict__ deg)
{
    int i = blockIdx.x * blockDim.x + threadIdx.x;
    if (i < N_NODES) deg[i] = 0;
}

__global__ void count_kernel(const int* __restrict__ dst, int* __restrict__ deg)
{
    int e = blockIdx.x * blockDim.x + threadIdx.x;
    if (e < N_EDGES) atomicAdd(&deg[dst[e]], 1);
}

__global__ __launch_bounds__(1024) void scan_kernel(
    const int* __restrict__ deg, int* __restrict__ rowstart,
    int* __restrict__ cursor, float* __restrict__ norm)
{
    __shared__ int sums[1024];
    const int t = threadIdx.x;
    const int L = (N_NODES + 1023) / 1024;   // 49
    int lo = t * L, hi = min(lo + L, N_NODES);
    int s = 0;
    for (int i = lo; i < hi; ++i) s += deg[i];
    sums[t] = s;
    __syncthreads();
    if (t == 0) {
        int run = 0;
        for (int i = 0; i < 1024; ++i) { int v = sums[i]; sums[i] = run; run += v; }
        rowstart[N_NODES] = run;
    }
    __syncthreads();
    int off = sums[t];
    for (int i = lo; i < hi; ++i) {
        int d = deg[i];
        rowstart[i] = off;
        cursor[i]   = off;
        norm[i]     = (d > 0) ? 1.f / (float)d : 0.f;
        off += d;
    }
}

__global__ void fill_kernel(const int* __restrict__ dst, int* __restrict__ cursor,
                            int* __restrict__ eidx)
{
    int e = blockIdx.x * blockDim.x + threadIdx.x;
    if (e < N_EDGES) {
        int pos = atomicAdd(&cursor[dst[e]], 1);
        eidx[pos] = e;
    }
}

// ---------------- aggregation (gather form) ----------------
__global__ __launch_bounds__(256) void aggregate_kernel(
    const float* __restrict__ hh, const float* __restrict__ dist,
    const int* __restrict__ src, const int* __restrict__ eidx,
    const int* __restrict__ rowstart, const float* __restrict__ norm,
    float* __restrict__ ahn)
{
    const int wave = threadIdx.x >> 6;
    const int lane = threadIdx.x & 63;
    const int v = blockIdx.x * 4 + wave;
    if (v >= N_NODES) return;
    const int r0 = rowstart[v], r1 = rowstart[v + 1];
    float a0 = 0.f, a1 = 0.f, a2 = 0.f;
    for (int k = r0; k < r1; ++k) {
        int e = eidx[k];
        int sn = src[e];
        float dv = dist[e];
        const float* hs = &hh[(size_t)sn * HID];
        a0 += hs[lane]       * dv;
        a1 += hs[lane + 64]  * dv;
        a2 += hs[lane + 128] * dv;
    }
    float nm = norm[v];
    ahn[(size_t)v * HID + lane]       = a0 * nm;
    ahn[(size_t)v * HID + lane + 64]  = a1 * nm;
    ahn[(size_t)v * HID + lane + 128] = a2 * nm;
}

// ---------------- GcnSAGE update ----------------
__global__ __launch_bounds__(192) void update_kernel(
    float* __restrict__ hh, const float* __restrict__ ahn,
    const float* __restrict__ W, const float* __restrict__ b,
    const float* __restrict__ g, const float* __restrict__ beta)
{
    __shared__ float hcs[16][HID2];      // 24.6 KB
    __shared__ float red[2][16][12];
    __shared__ float mv[2][16];
    const int tid = threadIdx.x;
    const int nbase = blockIdx.x * 16;

    for (int i = 0; i < 16; ++i) {
        int n = nbase + i;
        hcs[i][tid]       = hh[(size_t)n * HID + tid];
        hcs[i][HID + tid] = ahn[(size_t)n * HID + tid];
    }
    __syncthreads();

    float acc[16];
    float bb0 = b[tid];
    #pragma unroll
    for (int i = 0; i < 16; ++i) acc[i] = bb0;

    for (int d = 0; d < HID2; d += 4) {
        float w0 = W[(d + 0) * HID + tid];
        float w1 = W[(d + 1) * HID + tid];
        float w2 = W[(d + 2) * HID + tid];
        float w3 = W[(d + 3) * HID + tid];
        #pragma unroll
        for (int i = 0; i < 16; ++i) {
            float4 hv = *(const float4*)&hcs[i][d];
            acc[i] += hv.x * w0 + hv.y * w1 + hv.z * w2 + hv.w * w3;
        }
    }
    __syncthreads();
    float* ys = &hcs[0][0];
    #pragma unroll
    for (int i = 0; i < 16; ++i) ys[i * HID + tid] = acc[i];
    __syncthreads();
    {
        int i = tid / 12, j = tid % 12;
        float s = 0.f, s2 = 0.f;
        for (int k = j; k < HID; k += 12) { float v = ys[i * HID + k]; s += v; s2 += v * v; }
        red[0][i][j] = s; red[1][i][j] = s2;
    }
    __syncthreads();
    if (tid < 16) {
        float s = 0.f, s2 = 0.f;
        for (int j = 0; j < 12; ++j) { s += red[0][tid][j]; s2 += red[1][tid][j]; }
        float mean = s * (1.f / HID);
        float var  = s2 * (1.f / HID) - mean * mean;
        mv[0][tid] = mean;
        mv[1][tid] = rsqrtf(var + EPS);
    }
    __syncthreads();
    float gg = g[tid], be = beta[tid];
    #pragma unroll
    for (int i = 0; i < 16; ++i) {
        float y = (acc[i] - mv[0][i]) * mv[1][i] * gg + be;
        hh[(size_t)(nbase + i) * HID + tid] = (y > 0.f) ? y : 0.f;
    }
}

// ---------------- prep: W1 [192][96] f32 -> W1T bf16 [96][192] ----------------
__global__ void prep_w1t(const float* __restrict__ W1, unsigned short* __restrict__ w1t)
{
    int i = blockIdx.x * 256 + threadIdx.x;
    if (i < OUTC * HID) {
        int j = i / HID, k = i % HID;
        w1t[i] = f2bf(W1[k * OUTC + j]);
    }
}

// ---------------- edge MLP via MFMA ----------------
// 256 threads = 4 waves; 64 edges/block (wave w owns edges w*16..w*16+15).
// GEMM1: he[16x192] @ W1[192x96] via mfma_f32_16x16x32_bf16, 6 k-steps x 6 n-tiles.
// GEMM2 (96->2) in f32 registers + 16-lane shfl reduce.
// Edges processed in dst-sorted order (eidx) for gather locality; out scattered by orig id.
__global__ __launch_bounds__(256) void edge_mfma_kernel(
    const float* __restrict__ hh, const int* __restrict__ src, const int* __restrict__ dst,
    const int* __restrict__ eidx,
    const unsigned short* __restrict__ w1t, const float* __restrict__ b1,
    const float* __restrict__ W2, const float* __restrict__ b2,
    float* __restrict__ out)
{
    __shared__ unsigned short he[64][200];   // pad 192->200: conflict-free ds_read_b128
    __shared__ int sidx[64], didx[64], eor[64];
    const int tid = threadIdx.x;
    const int ebase = blockIdx.x * 64;

    if (tid < 64) {
        int e = eidx[ebase + tid];
        eor[tid] = e;
        sidx[tid] = src[e];
        didx[tid] = dst[e];
    }
    __syncthreads();

    const int w    = tid >> 6;
    const int lane = tid & 63;
    const int lo   = lane & 15;
    const int hi   = lane >> 4;

    // gather he = hh[src]*hh[dst] -> bf16 LDS (wave-private rows)
    for (int i = 0; i < 16; ++i) {
        int slot = w * 16 + i;
        const float* hs = &hh[(size_t)sidx[slot] * HID];
        const float* hd = &hh[(size_t)didx[slot] * HID];
        float p0 = hs[lane]       * hd[lane];
        float p1 = hs[lane + 64]  * hd[lane + 64];
        float p2 = hs[lane + 128] * hd[lane + 128];
        he[slot][lane]       = f2bf(p0);
        he[slot][lane + 64]  = f2bf(p1);
        he[slot][lane + 128] = f2bf(p2);
    }
    // no barrier: each wave reads only its own 16 rows (compiler orders LDS w->r)

    f32x4 acc[6];
    #pragma unroll
    for (int nt = 0; nt < 6; ++nt) acc[nt] = (f32x4){0.f, 0.f, 0.f, 0.f};

    #pragma unroll
    for (int kt = 0; kt < 6; ++kt) {
        const int k0 = kt * 32 + hi * 8;
        bf16x8 af = *(const bf16x8*)&he[w * 16 + lo][k0];
        #pragma unroll
        for (int nt = 0; nt < 6; ++nt) {
            bf16x8 bfr = *(const bf16x8*)&w1t[(size_t)(nt * 16 + lo) * HID + k0];
            acc[nt] = __builtin_amdgcn_mfma_f32_16x16x32_bf16(af, bfr, acc[nt], 0, 0, 0);
        }
    }

    // epilogue: relu(+b1) then @W2 (f32), reduce over 16 lanes sharing edge rows
    float b1c[6], w20[6], w21[6];
    #pragma unroll
    for (int nt = 0; nt < 6; ++nt) {
        int col = nt * 16 + lo;
        b1c[nt] = b1[col];
        w20[nt] = W2[col * 2 + 0];
        w21[nt] = W2[col * 2 + 1];
    }
    float bb0 = b2[0], bb1 = b2[1];
    #pragma unroll
    for (int reg = 0; reg < 4; ++reg) {
        float p0 = 0.f, p1 = 0.f;
        #pragma unroll
        for (int nt = 0; nt < 6; ++nt) {
            float hv = fmaxf(acc[nt][reg] + b1c[nt], 0.f);
            p0 += hv * w20[nt];
            p1 += hv * w21[nt];
        }
        #pragma unroll
        for (int off = 1; off < 16; off <<= 1) {
            p0 += __shfl_xor(p0, off, 64);
            p1 += __shfl_xor(p1, off, 64);
        }
        if (lo == 0) {
            int row = hi * 4 + reg;                 // edge within wave tile
            int e = eor[w * 16 + row];
            out[(size_t)e * 2 + 0] = p0 + bb0;
            out[(size_t)e * 2 + 1] = p1 + bb1;
        }
    }
}

// ---------------- launch ----------------
extern "C" void kernel_launch(void* const* d_in, const int* in_sizes, int n_in,
                              void* d_out, int out_size, void* d_ws, size_t ws_size,
                              hipStream_t stream)
{
    const float* h         = (const float*)d_in[0];
    const float* dist      = (const float*)d_in[1];
    const int*   src       = (const int*)  d_in[2];
    const int*   dst       = (const int*)  d_in[3];
    const float* proj_W    = (const float*)d_in[4];
    const float* proj_b    = (const float*)d_in[5];
    const float* proj_g    = (const float*)d_in[6];
    const float* proj_beta = (const float*)d_in[7];
    const float* gcn_W     = (const float*)d_in[8];
    const float* gcn_b     = (const float*)d_in[9];
    const float* gcn_g     = (const float*)d_in[10];
    const float* gcn_beta  = (const float*)d_in[11];
    const float* ep_W1     = (const float*)d_in[12];
    const float* ep_b1     = (const float*)d_in[13];
    const float* ep_W2     = (const float*)d_in[14];
    const float* ep_b2     = (const float*)d_in[15];
    float* out = (float*)d_out;

    char* p = (char*)d_ws;
    float* hh  = (float*)p;  p += (size_t)N_NODES * HID * sizeof(float);
    float* ahn = (float*)p;  p += (size_t)N_NODES * HID * sizeof(float);
    float* nrm = (float*)p;  p += (size_t)N_NODES * sizeof(float);
    int* deg      = (int*)p; p += (size_t)N_NODES * sizeof(int);
    int* rowstart = (int*)p; p += (size_t)(N_NODES + 1) * sizeof(int);
    int* cursor   = (int*)p; p += (size_t)N_NODES * sizeof(int);
    int* eidx     = (int*)p; p += (size_t)N_EDGES * sizeof(int);
    unsigned short* w1t = (unsigned short*)p; p += (size_t)OUTC * HID * sizeof(unsigned short);

    // projection + weight prep
    proj_kernel<<<(N_NODES + 7) / 8, 128, 0, stream>>>(h, proj_W, proj_b, proj_g, proj_beta, hh);
    prep_w1t<<<(OUTC * HID + 255) / 256, 256, 0, stream>>>(ep_W1, w1t);
    // CSR build
    zero_deg_kernel<<<(N_NODES + 255) / 256, 256, 0, stream>>>(deg);
    count_kernel<<<(N_EDGES + 255) / 256, 256, 0, stream>>>(dst, deg);
    scan_kernel<<<1, 1024, 0, stream>>>(deg, rowstart, cursor, nrm);
    fill_kernel<<<(N_EDGES + 255) / 256, 256, 0, stream>>>(dst, cursor, eidx);
    // 2 GcnSAGE layers
    for (int l = 0; l < 2; ++l) {
        aggregate_kernel<<<(N_NODES + 3) / 4, 256, 0, stream>>>(hh, dist, src, eidx, rowstart, nrm, ahn);
        update_kernel<<<N_NODES / 16, 192, 0, stream>>>(
            hh, ahn, gcn_W + (size_t)l * HID2 * HID, gcn_b + l * HID,
            gcn_g + l * HID, gcn_beta + l * HID);
    }
    // edge MLP (MFMA)
    edge_mfma_kernel<<<N_EDGES / 64, 256, 0, stream>>>(
        hh, src, dst, eidx, w1t, ep_b1, ep_W2, ep_b2, out);
}

// Round 7
// 831.065 us; speedup vs baseline: 1.4174x; 1.1856x over previous
//
#include <hip/hip_runtime.h>
#include <math.h>

#define N_NODES 50000
#define N_EDGES 400000
#define CHUNK   100
#define NCH     2
#define OUTC    96
#define HID     192      // NCH*OUTC
#define HID2    384      // 2*HID
#define EPS     1e-5f

typedef __bf16 bf16x8 __attribute__((ext_vector_type(8)));
typedef float  f32x4  __attribute__((ext_vector_type(4)));

__device__ inline unsigned short f2bf(float f) {
    unsigned int u = __float_as_uint(f);
    unsigned int r = (u + 0x7FFFu + ((u >> 16) & 1u)) >> 16;   // RNE
    return (unsigned short)r;
}

// ---------------- prep: edge W1 [192][96] f32 -> bf16 W1^T [96][192] ----------------
#define W1T_SZ (96 * 192)
__global__ void prep_w1t(const float* __restrict__ W1, unsigned short* __restrict__ w1t)
{
    int i = blockIdx.x * 256 + threadIdx.x;
    if (i < W1T_SZ) {
        int j = i / HID, k = i % HID;
        w1t[i] = f2bf(W1[k * OUTC + j]);
    }
}

// ---------------- projection, f32 column-parallel (update_kernel structure) ----------------
// 192 threads: thread = (chunk c, col j). 16 nodes/block. x staged in LDS (broadcast reads),
// W streamed coalesced from L2. Per-chunk LN(96) + LeakyReLU.
__global__ __launch_bounds__(192) void proj_kernel(
    const float* __restrict__ h, const float* __restrict__ W,
    const float* __restrict__ b, const float* __restrict__ g,
    const float* __restrict__ beta, float* __restrict__ hh)
{
    __shared__ float xs[16][NCH * CHUNK];   // 12.8 KB; reused as ys[16][192] after GEMM
    __shared__ float red[2][16][2][6];
    __shared__ float mv[2][16][2];
    const int tid = threadIdx.x;
    const int nbase = blockIdx.x * 16;

    for (int i = tid; i < 16 * 50; i += 192) {   // stage x as float4
        int row = i / 50, seg = i % 50;
        int n = nbase + row;
        float4 v = make_float4(0.f, 0.f, 0.f, 0.f);
        if (n < N_NODES) v = *(const float4*)&h[(size_t)n * (NCH * CHUNK) + seg * 4];
        *(float4*)&xs[row][seg * 4] = v;
    }
    __syncthreads();

    const int c = tid / OUTC, j = tid % OUTC;
    const float* wc = &W[c * CHUNK * OUTC];

    float acc[16];
    float bb = b[c * OUTC + j];
    #pragma unroll
    for (int i = 0; i < 16; ++i) acc[i] = bb;

    for (int d = 0; d < CHUNK; d += 4) {    // 25 steps
        float w0 = wc[(d + 0) * OUTC + j];
        float w1 = wc[(d + 1) * OUTC + j];
        float w2 = wc[(d + 2) * OUTC + j];
        float w3 = wc[(d + 3) * OUTC + j];
        #pragma unroll
        for (int i = 0; i < 16; ++i) {
            float4 hv = *(const float4*)&xs[i][c * CHUNK + d];
            acc[i] += hv.x * w0 + hv.y * w1 + hv.z * w2 + hv.w * w3;
        }
    }
    __syncthreads();
    // LN per (node, chunk): reuse xs as ys[16][192]
    float* ys = &xs[0][0];
    #pragma unroll
    for (int i = 0; i < 16; ++i) ys[i * HID + c * OUTC + j] = acc[i];
    __syncthreads();
    {
        int grp = tid / 6, q = tid % 6;       // 32 groups = 16 nodes x 2 chunks
        int gi = grp >> 1, gc = grp & 1;
        float s = 0.f, s2 = 0.f;
        #pragma unroll
        for (int t = 0; t < 16; ++t) {
            float v = ys[gi * HID + gc * OUTC + q + 6 * t];
            s += v; s2 += v * v;
        }
        red[0][gi][gc][q] = s; red[1][gi][gc][q] = s2;
    }
    __syncthreads();
    if (tid < 32) {
        int gi = tid >> 1, gc = tid & 1;
        float s = 0.f, s2 = 0.f;
        #pragma unroll
        for (int q = 0; q < 6; ++q) { s += red[0][gi][gc][q]; s2 += red[1][gi][gc][q]; }
        float mean = s * (1.f / 96.f);
        float var  = s2 * (1.f / 96.f) - mean * mean;
        mv[0][gi][gc] = mean;
        mv[1][gi][gc] = rsqrtf(var + EPS);
    }
    __syncthreads();
    float gg = g[c * OUTC + j], be = beta[c * OUTC + j];
    #pragma unroll
    for (int i = 0; i < 16; ++i) {
        int n = nbase + i;
        if (n < N_NODES) {
            float y = (acc[i] - mv[0][i][c]) * mv[1][i][c] * gg + be;
            y = (y < 0.f) ? 0.01f * y : y;
            hh[(size_t)n * HID + c * OUTC + j] = y;
        }
    }
}

// ---------------- CSR build ----------------
__global__ void zero_deg_kernel(int* __restrict__ deg)
{
    int i = blockIdx.x * blockDim.x + threadIdx.x;
    if (i < N_NODES) deg[i] = 0;
}

__global__ void count_kernel(const int* __restrict__ dst, int* __restrict__ deg)
{
    int e = blockIdx.x * blockDim.x + threadIdx.x;
    if (e < N_EDGES) atomicAdd(&deg[dst[e]], 1);
}

__global__ __launch_bounds__(1024) void scan_kernel(
    const int* __restrict__ deg, int* __restrict__ rowstart,
    int* __restrict__ cursor, float* __restrict__ norm)
{
    __shared__ int sums[1024];
    const int t = threadIdx.x;
    const int L = (N_NODES + 1023) / 1024;   // 49
    int lo = t * L, hi = min(lo + L, N_NODES);
    int s = 0;
    for (int i = lo; i < hi; ++i) s += deg[i];
    sums[t] = s;
    __syncthreads();
    if (t == 0) {
        int run = 0;
        for (int i = 0; i < 1024; ++i) { int v = sums[i]; sums[i] = run; run += v; }
        rowstart[N_NODES] = run;
    }
    __syncthreads();
    int off = sums[t];
    for (int i = lo; i < hi; ++i) {
        int d = deg[i];
        rowstart[i] = off;
        cursor[i]   = off;
        norm[i]     = (d > 0) ? 1.f / (float)d : 0.f;
        off += d;
    }
}

// payload CSR: store edge id (for edge kernel) AND (src, dist) (for aggregate)
__global__ void fill_kernel(const int* __restrict__ src, const int* __restrict__ dst,
                            const float* __restrict__ dist, int* __restrict__ cursor,
                            int* __restrict__ eidx, int* __restrict__ csr_src,
                            float* __restrict__ csr_dist)
{
    int e = blockIdx.x * blockDim.x + threadIdx.x;
    if (e < N_EDGES) {
        int pos = atomicAdd(&cursor[dst[e]], 1);
        eidx[pos]     = e;
        csr_src[pos]  = src[e];
        csr_dist[pos] = dist[e];
    }
}

// ---------------- aggregation (gather form, payload CSR, unroll x2) ----------------
__global__ __launch_bounds__(256) void aggregate_kernel(
    const float* __restrict__ hh, const int* __restrict__ csr_src,
    const float* __restrict__ csr_dist, const int* __restrict__ rowstart,
    const float* __restrict__ norm, float* __restrict__ ahn)
{
    const int wave = threadIdx.x >> 6;
    const int lane = threadIdx.x & 63;
    const int v = blockIdx.x * 4 + wave;
    if (v >= N_NODES) return;
    const int r0 = rowstart[v], r1 = rowstart[v + 1];
    float a0 = 0.f, a1 = 0.f, a2 = 0.f;
    int k = r0;
    for (; k + 1 < r1; k += 2) {
        int   s0 = csr_src[k],      s1 = csr_src[k + 1];
        float d0 = csr_dist[k],     d1 = csr_dist[k + 1];
        const float* h0 = &hh[(size_t)s0 * HID];
        const float* h1 = &hh[(size_t)s1 * HID];
        a0 += h0[lane]       * d0 + h1[lane]       * d1;
        a1 += h0[lane + 64]  * d0 + h1[lane + 64]  * d1;
        a2 += h0[lane + 128] * d0 + h1[lane + 128] * d1;
    }
    if (k < r1) {
        int s0 = csr_src[k];
        float d0 = csr_dist[k];
        const float* h0 = &hh[(size_t)s0 * HID];
        a0 += h0[lane] * d0; a1 += h0[lane + 64] * d0; a2 += h0[lane + 128] * d0;
    }
    float nm = norm[v];
    ahn[(size_t)v * HID + lane]       = a0 * nm;
    ahn[(size_t)v * HID + lane + 64]  = a1 * nm;
    ahn[(size_t)v * HID + lane + 128] = a2 * nm;
}

// ---------------- GcnSAGE update (R2 verbatim, f32) ----------------
__global__ __launch_bounds__(192) void update_kernel(
    float* __restrict__ hh, const float* __restrict__ ahn,
    const float* __restrict__ W, const float* __restrict__ b,
    const float* __restrict__ g, const float* __restrict__ beta)
{
    __shared__ float hcs[16][HID2];      // 24.6 KB
    __shared__ float red[2][16][12];
    __shared__ float mv[2][16];
    const int tid = threadIdx.x;
    const int nbase = blockIdx.x * 16;

    for (int i = 0; i < 16; ++i) {
        int n = nbase + i;
        hcs[i][tid]       = hh[(size_t)n * HID + tid];
        hcs[i][HID + tid] = ahn[(size_t)n * HID + tid];
    }
    __syncthreads();

    float acc[16];
    float bb0 = b[tid];
    #pragma unroll
    for (int i = 0; i < 16; ++i) acc[i] = bb0;

    for (int d = 0; d < HID2; d += 4) {
        float w0 = W[(d + 0) * HID + tid];
        float w1 = W[(d + 1) * HID + tid];
        float w2 = W[(d + 2) * HID + tid];
        float w3 = W[(d + 3) * HID + tid];
        #pragma unroll
        for (int i = 0; i < 16; ++i) {
            float4 hv = *(const float4*)&hcs[i][d];
            acc[i] += hv.x * w0 + hv.y * w1 + hv.z * w2 + hv.w * w3;
        }
    }
    __syncthreads();
    float* ys = &hcs[0][0];
    #pragma unroll
    for (int i = 0; i < 16; ++i) ys[i * HID + tid] = acc[i];
    __syncthreads();
    {
        int i = tid / 12, j = tid % 12;
        float s = 0.f, s2 = 0.f;
        for (int k = j; k < HID; k += 12) { float v = ys[i * HID + k]; s += v; s2 += v * v; }
        red[0][i][j] = s; red[1][i][j] = s2;
    }
    __syncthreads();
    if (tid < 16) {
        float s = 0.f, s2 = 0.f;
        for (int j = 0; j < 12; ++j) { s += red[0][tid][j]; s2 += red[1][tid][j]; }
        float mean = s * (1.f / HID);
        float var  = s2 * (1.f / HID) - mean * mean;
        mv[0][tid] = mean;
        mv[1][tid] = rsqrtf(var + EPS);
    }
    __syncthreads();
    float gg = g[tid], be = beta[tid];
    #pragma unroll
    for (int i = 0; i < 16; ++i) {
        float y = (acc[i] - mv[0][i]) * mv[1][i] * gg + be;
        hh[(size_t)(nbase + i) * HID + tid] = (y > 0.f) ? y : 0.f;
    }
}

// ---------------- edge MLP via MFMA (R2 verbatim, bf16 — proven 3.9e-3) ----------------
__global__ __launch_bounds__(256) void edge_mfma_kernel(
    const float* __restrict__ hh, const int* __restrict__ src, const int* __restrict__ dst,
    const int* __restrict__ eidx,
    const unsigned short* __restrict__ w1t, const float* __restrict__ b1,
    const float* __restrict__ W2, const float* __restrict__ b2,
    float* __restrict__ out)
{
    __shared__ unsigned short he[64][200];   // 100 dw stride == 4 mod 32: conflict-free (R2)
    __shared__ int sidx[64], didx[64], eor[64];
    const int tid = threadIdx.x;
    const int ebase = blockIdx.x * 64;

    if (tid < 64) {
        int e = eidx[ebase + tid];
        eor[tid] = e;
        sidx[tid] = src[e];
        didx[tid] = dst[e];
    }
    __syncthreads();

    const int w    = tid >> 6;
    const int lane = tid & 63;
    const int lo   = lane & 15;
    const int hi   = lane >> 4;

    for (int i = 0; i < 16; ++i) {     // wave-private rows -> no 2nd barrier
        int slot = w * 16 + i;
        const float* hs = &hh[(size_t)sidx[slot] * HID];
        const float* hd = &hh[(size_t)didx[slot] * HID];
        float p0 = hs[lane]       * hd[lane];
        float p1 = hs[lane + 64]  * hd[lane + 64];
        float p2 = hs[lane + 128] * hd[lane + 128];
        he[slot][lane]       = f2bf(p0);
        he[slot][lane + 64]  = f2bf(p1);
        he[slot][lane + 128] = f2bf(p2);
    }

    f32x4 acc[6];
    #pragma unroll
    for (int nt = 0; nt < 6; ++nt) acc[nt] = (f32x4){0.f, 0.f, 0.f, 0.f};

    #pragma unroll
    for (int kt = 0; kt < 6; ++kt) {
        const int k0 = kt * 32 + hi * 8;
        bf16x8 af = *(const bf16x8*)&he[w * 16 + lo][k0];
        #pragma unroll
        for (int nt = 0; nt < 6; ++nt) {
            bf16x8 bfr = *(const bf16x8*)&w1t[(size_t)(nt * 16 + lo) * HID + k0];
            acc[nt] = __builtin_amdgcn_mfma_f32_16x16x32_bf16(af, bfr, acc[nt], 0, 0, 0);
        }
    }

    float b1c[6], w20[6], w21[6];
    #pragma unroll
    for (int nt = 0; nt < 6; ++nt) {
        int col = nt * 16 + lo;
        b1c[nt] = b1[col];
        w20[nt] = W2[col * 2 + 0];
        w21[nt] = W2[col * 2 + 1];
    }
    float bb0 = b2[0], bb1 = b2[1];
    #pragma unroll
    for (int reg = 0; reg < 4; ++reg) {
        float p0 = 0.f, p1 = 0.f;
        #pragma unroll
        for (int nt = 0; nt < 6; ++nt) {
            float hv = fmaxf(acc[nt][reg] + b1c[nt], 0.f);
            p0 += hv * w20[nt];
            p1 += hv * w21[nt];
        }
        #pragma unroll
        for (int off = 1; off < 16; off <<= 1) {
            p0 += __shfl_xor(p0, off, 64);
            p1 += __shfl_xor(p1, off, 64);
        }
        if (lo == 0) {
            int row = hi * 4 + reg;
            int e = eor[w * 16 + row];
            out[(size_t)e * 2 + 0] = p0 + bb0;
            out[(size_t)e * 2 + 1] = p1 + bb1;
        }
    }
}

// ---------------- launch ----------------
extern "C" void kernel_launch(void* const* d_in, const int* in_sizes, int n_in,
                              void* d_out, int out_size, void* d_ws, size_t ws_size,
                              hipStream_t stream)
{
    const float* h         = (const float*)d_in[0];
    const float* dist      = (const float*)d_in[1];
    const int*   src       = (const int*)  d_in[2];
    const int*   dst       = (const int*)  d_in[3];
    const float* proj_W    = (const float*)d_in[4];
    const float* proj_b    = (const float*)d_in[5];
    const float* proj_g    = (const float*)d_in[6];
    const float* proj_beta = (const float*)d_in[7];
    const float* gcn_W     = (const float*)d_in[8];
    const float* gcn_b     = (const float*)d_in[9];
    const float* gcn_g     = (const float*)d_in[10];
    const float* gcn_beta  = (const float*)d_in[11];
    const float* ep_W1     = (const float*)d_in[12];
    const float* ep_b1     = (const float*)d_in[13];
    const float* ep_W2     = (const float*)d_in[14];
    const float* ep_b2     = (const float*)d_in[15];
    float* out = (float*)d_out;

    char* p = (char*)d_ws;
    float* hh  = (float*)p;  p += (size_t)N_NODES * HID * sizeof(float);
    float* ahn = (float*)p;  p += (size_t)N_NODES * HID * sizeof(float);
    float* nrm = (float*)p;  p += (size_t)N_NODES * sizeof(float);
    int* deg      = (int*)p; p += (size_t)N_NODES * sizeof(int);
    int* rowstart = (int*)p; p += (size_t)(N_NODES + 1) * sizeof(int);
    int* cursor   = (int*)p; p += (size_t)N_NODES * sizeof(int);
    int* eidx     = (int*)p; p += (size_t)N_EDGES * sizeof(int);
    int* csr_src  = (int*)p; p += (size_t)N_EDGES * sizeof(int);
    float* csr_dist = (float*)p; p += (size_t)N_EDGES * sizeof(float);
    p = (char*)(((uintptr_t)p + 255) & ~(uintptr_t)255);
    unsigned short* w1t = (unsigned short*)p; p += (size_t)W1T_SZ * sizeof(unsigned short);

    // prep + projection (f32 column-parallel)
    prep_w1t<<<(W1T_SZ + 255) / 256, 256, 0, stream>>>(ep_W1, w1t);
    proj_kernel<<<(N_NODES + 15) / 16, 192, 0, stream>>>(
        h, proj_W, proj_b, proj_g, proj_beta, hh);
    // CSR build (payload)
    zero_deg_kernel<<<(N_NODES + 255) / 256, 256, 0, stream>>>(deg);
    count_kernel<<<(N_EDGES + 255) / 256, 256, 0, stream>>>(dst, deg);
    scan_kernel<<<1, 1024, 0, stream>>>(deg, rowstart, cursor, nrm);
    fill_kernel<<<(N_EDGES + 255) / 256, 256, 0, stream>>>(
        src, dst, dist, cursor, eidx, csr_src, csr_dist);
    // 2 GcnSAGE layers (f32 update — R2 verbatim)
    for (int l = 0; l < 2; ++l) {
        aggregate_kernel<<<(N_NODES + 3) / 4, 256, 0, stream>>>(
            hh, csr_src, csr_dist, rowstart, nrm, ahn);
        update_kernel<<<N_NODES / 16, 192, 0, stream>>>(
            hh, ahn, gcn_W + (size_t)l * HID2 * HID, gcn_b + l * HID,
            gcn_g + l * HID, gcn_beta + l * HID);
    }
    // edge MLP (MFMA, bf16 — R2 verbatim)
    edge_mfma_kernel<<<N_EDGES / 64, 256, 0, stream>>>(
        hh, src, dst, eidx, w1t, ep_b1, ep_W2, ep_b2, out);
}